// Round 4
// baseline (98.317 us; speedup 1.0000x reference)
//
#include <hip/hip_runtime.h>
#include <math.h>

#define DD 512
#define BB 128
#define MM 1024
#define MARGINF 9.0f
#define EPSF 1e-6f
#define NREC (BB * MM)     // 131072
#define NBINS 102400       // padded to 1024*100; real v in [0,100000)
#define BINS_PER_T 100

// ---- workspace layout (bytes) ----
#define HEADS_OFF 0u        // 128*512*4 = 262144
#define BHEAD_OFF 262144u   // 128*4
#define COUNTS_OFF 266240u  // NBINS*4 = 409600
#define CURSOR_OFF 675840u  // NBINS*4 = 409600
#define SV_OFF 1085440u     // NREC*4
#define SBM_OFF 1609728u    // NREC*4

// ---------------- zero counts+cursor (contiguous 2*NBINS ints) ------------
__global__ __launch_bounds__(256) void zero_kernel(int* __restrict__ p, int n) {
  int i = blockIdx.x * 256 + threadIdx.x;
  if (i < n) p[i] = 0;
}

// ---------------- histogram over v ----------------
__global__ __launch_bounds__(256) void hist_kernel(const int* __restrict__ v_idx,
                                                   int* __restrict__ counts) {
  int i = blockIdx.x * 256 + threadIdx.x;
  atomicAdd(counts + v_idx[i], 1);
}

// ---------------- exclusive scan of 102400 bins (1 block, 1024 thr) -------
__global__ __launch_bounds__(1024) void scan_kernel(const int* __restrict__ counts,
                                                    int* __restrict__ cursor) {
  __shared__ int lds[1024];
  const int t = threadIdx.x;
  const int base = t * BINS_PER_T;
  int s = 0;
  for (int j = 0; j < BINS_PER_T; ++j) s += counts[base + j];
  lds[t] = s;
  __syncthreads();
  for (int st = 1; st < 1024; st <<= 1) {
    int x = (t >= st) ? lds[t - st] : 0;
    __syncthreads();
    lds[t] += x;
    __syncthreads();
  }
  int run = lds[t] - s;  // exclusive prefix of this thread's segment
  for (int j = 0; j < BINS_PER_T; ++j) {
    int c = counts[base + j];
    cursor[base + j] = run;
    run += c;
  }
}

// ---------------- scatter records into sorted order ----------------
__global__ __launch_bounds__(256) void scatter_kernel(const int* __restrict__ v_idx,
                                                      int* __restrict__ cursor,
                                                      int* __restrict__ sv,
                                                      int* __restrict__ sbm) {
  int i = blockIdx.x * 256 + threadIdx.x;
  int v = v_idx[i];
  int pos = atomicAdd(cursor + v, 1);
  sv[pos] = v;
  sbm[pos] = i;  // i = b*MM + m == out index
}

// ---------------- head transform (verified round-1 kernel + bias fold) ----
__global__ __launch_bounds__(64) void head_prep_kernel(
    const int* __restrict__ u_idx, const int* __restrict__ r_idx,
    const float* __restrict__ emb, const float* __restrict__ rrot,
    const float* __restrict__ rcen, const float* __restrict__ rtrans,
    const float* __restrict__ bias_head, float* __restrict__ heads,
    float* __restrict__ bhead) {
  const int b = blockIdx.x;
  const int lane = threadIdx.x;
  const int u = u_idx[b];
  const int r = r_idx[b];

  const float4* hrow = (const float4*)(emb + (size_t)u * DD);
  float4 h0 = hrow[2 * lane];
  float4 h1 = hrow[2 * lane + 1];

  float ss = h0.x * h0.x + h0.y * h0.y + h0.z * h0.z + h0.w * h0.w +
             h1.x * h1.x + h1.y * h1.y + h1.z * h1.z + h1.w * h1.w;
#pragma unroll
  for (int off = 32; off; off >>= 1) ss += __shfl_xor(ss, off, 64);
  float un = fmaxf(sqrtf(ss), 1e-15f);
  float scale = tanhf(un) / un;

  const float4* grow = (const float4*)(rrot + (size_t)r * DD);
  const float4* crow = (const float4*)(rcen + (size_t)r * DD);
  const float4* trow = (const float4*)(rtrans + (size_t)r * DD);
  float4 g0 = grow[2 * lane], g1 = grow[2 * lane + 1];
  float4 c0 = crow[2 * lane], c1 = crow[2 * lane + 1];
  float4 t0 = trow[2 * lane], t1 = trow[2 * lane + 1];

  float4 x0, x1;
  x0.x = h0.x * scale + c0.x; x0.y = h0.y * scale + c0.y;
  x0.z = h0.z * scale + c0.z; x0.w = h0.w * scale + c0.w;
  x1.x = h1.x * scale + c1.x; x1.y = h1.y * scale + c1.y;
  x1.z = h1.z * scale + c1.z; x1.w = h1.w * scale + c1.w;

  float4 o0, o1;
  {
    float gn = fmaxf(sqrtf(g0.x * g0.x + g0.y * g0.y), 1e-15f);
    float cc = g0.x / gn, sn = g0.y / gn;
    o0.x = cc * x0.x - sn * x0.y;
    o0.y = cc * x0.y + sn * x0.x;
  }
  {
    float gn = fmaxf(sqrtf(g0.z * g0.z + g0.w * g0.w), 1e-15f);
    float cc = g0.z / gn, sn = g0.w / gn;
    o0.z = cc * x0.z - sn * x0.w;
    o0.w = cc * x0.w + sn * x0.z;
  }
  {
    float gn = fmaxf(sqrtf(g1.x * g1.x + g1.y * g1.y), 1e-15f);
    float cc = g1.x / gn, sn = g1.y / gn;
    o1.x = cc * x1.x - sn * x1.y;
    o1.y = cc * x1.y + sn * x1.x;
  }
  {
    float gn = fmaxf(sqrtf(g1.z * g1.z + g1.w * g1.w), 1e-15f);
    float cc = g1.z / gn, sn = g1.w / gn;
    o1.z = cc * x1.z - sn * x1.w;
    o1.w = cc * x1.w + sn * x1.z;
  }
  o0.x = o0.x - c0.x + t0.x + EPSF; o0.y = o0.y - c0.y + t0.y + EPSF;
  o0.z = o0.z - c0.z + t0.z + EPSF; o0.w = o0.w - c0.w + t0.w + EPSF;
  o1.x = o1.x - c1.x + t1.x + EPSF; o1.y = o1.y - c1.y + t1.y + EPSF;
  o1.z = o1.z - c1.z + t1.z + EPSF; o1.w = o1.w - c1.w + t1.w + EPSF;

  float4* orow = (float4*)(heads + (size_t)b * DD);
  orow[2 * lane] = o0;
  orow[2 * lane + 1] = o1;
  if (lane == 0) bhead[b] = MARGINF + bias_head[u];
}

// ---------------- sorted-order distance kernel ----------------
// 2048 blocks x 256 thr; XCD-swizzled chunk of 64 records; wave = 16 records.
__global__ __launch_bounds__(256) void dist_kernel(
    const int* __restrict__ sv, const int* __restrict__ sbm,
    const float* __restrict__ emb, const float* __restrict__ heads,
    const float* __restrict__ bhead, const float* __restrict__ bias_tail,
    float* __restrict__ out) {
  const int bid = blockIdx.x;
  const int chunk = (bid & 7) * 256 + (bid >> 3);  // bijective: 2048 % 8 == 0
  const int wid = threadIdx.x >> 6;
  const int lane = threadIdx.x & 63;
  const int rbase = chunk * 64 + wid * 16;

  const int4* svp = (const int4*)(sv + rbase);
  const int4* sbp = (const int4*)(sbm + rbase);
  const int4 V0 = svp[0], V1 = svp[1], V2 = svp[2], V3 = svp[3];
  const int4 Q0 = sbp[0], Q1 = sbp[1], Q2 = sbp[2], Q3 = sbp[3];

#define GROUP(vv, qq)                                                         \
  do {                                                                        \
    const float4* tA = (const float4*)(emb + (size_t)(vv).x * DD);            \
    const float4* tB = (const float4*)(emb + (size_t)(vv).y * DD);            \
    const float4* tC = (const float4*)(emb + (size_t)(vv).z * DD);            \
    const float4* tD = (const float4*)(emb + (size_t)(vv).w * DD);            \
    const float4* hA = (const float4*)(heads + (size_t)((qq).x >> 10) * DD);  \
    const float4* hB = (const float4*)(heads + (size_t)((qq).y >> 10) * DD);  \
    const float4* hC = (const float4*)(heads + (size_t)((qq).z >> 10) * DD);  \
    const float4* hD = (const float4*)(heads + (size_t)((qq).w >> 10) * DD);  \
    float4 a0 = tA[lane], a1 = tA[64 + lane];                                 \
    float4 b0 = tB[lane], b1 = tB[64 + lane];                                 \
    float4 c0 = tC[lane], c1 = tC[64 + lane];                                 \
    float4 d0 = tD[lane], d1 = tD[64 + lane];                                 \
    float4 p0 = hA[lane], p1 = hA[64 + lane];                                 \
    float4 q0 = hB[lane], q1 = hB[64 + lane];                                 \
    float4 r0 = hC[lane], r1 = hC[64 + lane];                                 \
    float4 s0 = hD[lane], s1 = hD[64 + lane];                                 \
    float bt0 = bias_tail[(vv).x], bt1 = bias_tail[(vv).y];                   \
    float bt2 = bias_tail[(vv).z], bt3 = bias_tail[(vv).w];                   \
    float d_, ra, rb, rc, rd;                                                 \
    d_ = p0.x - a0.x; ra = d_ * d_;                                           \
    d_ = p0.y - a0.y; ra += d_ * d_;                                          \
    d_ = p0.z - a0.z; ra += d_ * d_;                                          \
    d_ = p0.w - a0.w; ra += d_ * d_;                                          \
    d_ = p1.x - a1.x; ra += d_ * d_;                                          \
    d_ = p1.y - a1.y; ra += d_ * d_;                                          \
    d_ = p1.z - a1.z; ra += d_ * d_;                                          \
    d_ = p1.w - a1.w; ra += d_ * d_;                                          \
    d_ = q0.x - b0.x; rb = d_ * d_;                                           \
    d_ = q0.y - b0.y; rb += d_ * d_;                                          \
    d_ = q0.z - b0.z; rb += d_ * d_;                                          \
    d_ = q0.w - b0.w; rb += d_ * d_;                                          \
    d_ = q1.x - b1.x; rb += d_ * d_;                                          \
    d_ = q1.y - b1.y; rb += d_ * d_;                                          \
    d_ = q1.z - b1.z; rb += d_ * d_;                                          \
    d_ = q1.w - b1.w; rb += d_ * d_;                                          \
    d_ = r0.x - c0.x; rc = d_ * d_;                                           \
    d_ = r0.y - c0.y; rc += d_ * d_;                                          \
    d_ = r0.z - c0.z; rc += d_ * d_;                                          \
    d_ = r0.w - c0.w; rc += d_ * d_;                                          \
    d_ = r1.x - c1.x; rc += d_ * d_;                                          \
    d_ = r1.y - c1.y; rc += d_ * d_;                                          \
    d_ = r1.z - c1.z; rc += d_ * d_;                                          \
    d_ = r1.w - c1.w; rc += d_ * d_;                                          \
    d_ = s0.x - d0.x; rd = d_ * d_;                                           \
    d_ = s0.y - d0.y; rd += d_ * d_;                                          \
    d_ = s0.z - d0.z; rd += d_ * d_;                                          \
    d_ = s0.w - d0.w; rd += d_ * d_;                                          \
    d_ = s1.x - d1.x; rd += d_ * d_;                                          \
    d_ = s1.y - d1.y; rd += d_ * d_;                                          \
    d_ = s1.z - d1.z; rd += d_ * d_;                                          \
    d_ = s1.w - d1.w; rd += d_ * d_;                                          \
    _Pragma("unroll")                                                         \
    for (int o_ = 32; o_; o_ >>= 1) {                                         \
      ra += __shfl_xor(ra, o_, 64);                                           \
      rb += __shfl_xor(rb, o_, 64);                                           \
      rc += __shfl_xor(rc, o_, 64);                                           \
      rd += __shfl_xor(rd, o_, 64);                                           \
    }                                                                         \
    if (lane == 0) {                                                          \
      out[(qq).x] = bhead[(qq).x >> 10] - sqrtf(ra) + bt0;                    \
      out[(qq).y] = bhead[(qq).y >> 10] - sqrtf(rb) + bt1;                    \
      out[(qq).z] = bhead[(qq).z >> 10] - sqrtf(rc) + bt2;                    \
      out[(qq).w] = bhead[(qq).w >> 10] - sqrtf(rd) + bt3;                    \
    }                                                                         \
  } while (0)

  GROUP(V0, Q0);
  GROUP(V1, Q1);
  GROUP(V2, Q2);
  GROUP(V3, Q3);
#undef GROUP
}

extern "C" void kernel_launch(void* const* d_in, const int* in_sizes, int n_in,
                              void* d_out, int out_size, void* d_ws, size_t ws_size,
                              hipStream_t stream) {
  const int* u_idx = (const int*)d_in[0];
  const int* r_idx = (const int*)d_in[1];
  const int* v_idx = (const int*)d_in[2];
  const float* emb = (const float*)d_in[3];
  const float* rrot = (const float*)d_in[4];
  const float* rcen = (const float*)d_in[5];
  const float* rtrans = (const float*)d_in[6];
  const float* bias_head = (const float*)d_in[7];
  const float* bias_tail = (const float*)d_in[8];
  float* out = (float*)d_out;

  char* ws = (char*)d_ws;
  float* heads = (float*)(ws + HEADS_OFF);
  float* bhead = (float*)(ws + BHEAD_OFF);
  int* counts = (int*)(ws + COUNTS_OFF);
  int* cursor = (int*)(ws + CURSOR_OFF);
  int* sv = (int*)(ws + SV_OFF);
  int* sbm = (int*)(ws + SBM_OFF);

  // counts+cursor are contiguous: zero both in one pass (2*NBINS ints)
  zero_kernel<<<(2 * NBINS + 255) / 256, 256, 0, stream>>>(counts, 2 * NBINS);
  hist_kernel<<<NREC / 256, 256, 0, stream>>>(v_idx, counts);
  scan_kernel<<<1, 1024, 0, stream>>>(counts, cursor);
  scatter_kernel<<<NREC / 256, 256, 0, stream>>>(v_idx, cursor, sv, sbm);
  head_prep_kernel<<<BB, 64, 0, stream>>>(u_idx, r_idx, emb, rrot, rcen, rtrans,
                                          bias_head, heads, bhead);
  dist_kernel<<<NREC / 64, 256, 0, stream>>>(sv, sbm, emb, heads, bhead,
                                             bias_tail, out);
}

// Round 5
// 46.282 us; speedup vs baseline: 2.1243x; 2.1243x over previous
//
#include <hip/hip_runtime.h>
#include <math.h>

#define DD 512
#define BB 128
#define MM 1024
#define MARGIN 9.0f
#define EPSF 1e-6f
#define SPLIT 16  // blocks per head row; each block covers MM/SPLIT = 64 m's

// One fused kernel. grid = B*SPLIT blocks x 256 threads (4 waves).
// Each wave: recompute transformed head (cheap, L2-hot), then 16 m's as
// 4 iterations x 4 independent gather chains. Lane i owns row floats
// [8i, 8i+8) -> two float4 loads, fully coalesced 2KB per row per wave.
// NOTE (r3/r4 post-mortems): explicit SW pipelining = null (not MLP-bound:
// ~128KB/CU in flight vs ~10KB needed); v-sort L2-dedup = 2x SLOWER (sort
// machinery + head-load doubling exceed the 1.31x re-read prize). This
// structure is at ~89% of the streaming-copy ceiling on a random gather.
__global__ __launch_bounds__(256) void roth_fused_kernel(
    const int* __restrict__ u_idx,
    const int* __restrict__ r_idx,
    const int* __restrict__ v_idx,
    const float* __restrict__ emb,
    const float* __restrict__ rrot,
    const float* __restrict__ rcen,
    const float* __restrict__ rtrans,
    const float* __restrict__ bias_head,
    const float* __restrict__ bias_tail,
    float* __restrict__ out) {
  const int b = blockIdx.x / SPLIT;
  const int s = blockIdx.x % SPLIT;
  const int wid = threadIdx.x >> 6;
  const int lane = threadIdx.x & 63;
  const int u = u_idx[b];
  const int r = r_idx[b];

  // ---------------- head transform (redundant per wave; rows are L2-hot) ---
  const float4* hrow = (const float4*)(emb + (size_t)u * DD);
  float4 hh0 = hrow[2 * lane];
  float4 hh1 = hrow[2 * lane + 1];

  float ss = hh0.x * hh0.x + hh0.y * hh0.y + hh0.z * hh0.z + hh0.w * hh0.w +
             hh1.x * hh1.x + hh1.y * hh1.y + hh1.z * hh1.z + hh1.w * hh1.w;
  for (int off = 32; off; off >>= 1) ss += __shfl_xor(ss, off, 64);
  float un = fmaxf(sqrtf(ss), 1e-15f);
  float scale = tanhf(un) / un;  // sqrt_c = 1

  const float4* grow = (const float4*)(rrot + (size_t)r * DD);
  const float4* crow = (const float4*)(rcen + (size_t)r * DD);
  const float4* trow = (const float4*)(rtrans + (size_t)r * DD);
  float4 g0 = grow[2 * lane], g1 = grow[2 * lane + 1];
  float4 c0 = crow[2 * lane], c1 = crow[2 * lane + 1];
  float4 t0 = trow[2 * lane], t1 = trow[2 * lane + 1];

  float4 x0, x1;
  x0.x = hh0.x * scale + c0.x; x0.y = hh0.y * scale + c0.y;
  x0.z = hh0.z * scale + c0.z; x0.w = hh0.w * scale + c0.w;
  x1.x = hh1.x * scale + c1.x; x1.y = hh1.y * scale + c1.y;
  x1.z = hh1.z * scale + c1.z; x1.w = hh1.w * scale + c1.w;

  float4 h0, h1;  // transformed head (+EPS folded)
  {
    float gn = fmaxf(sqrtf(g0.x * g0.x + g0.y * g0.y), 1e-15f);
    float cc = g0.x / gn, sn = g0.y / gn;
    h0.x = cc * x0.x - sn * x0.y;
    h0.y = cc * x0.y + sn * x0.x;
  }
  {
    float gn = fmaxf(sqrtf(g0.z * g0.z + g0.w * g0.w), 1e-15f);
    float cc = g0.z / gn, sn = g0.w / gn;
    h0.z = cc * x0.z - sn * x0.w;
    h0.w = cc * x0.w + sn * x0.z;
  }
  {
    float gn = fmaxf(sqrtf(g1.x * g1.x + g1.y * g1.y), 1e-15f);
    float cc = g1.x / gn, sn = g1.y / gn;
    h1.x = cc * x1.x - sn * x1.y;
    h1.y = cc * x1.y + sn * x1.x;
  }
  {
    float gn = fmaxf(sqrtf(g1.z * g1.z + g1.w * g1.w), 1e-15f);
    float cc = g1.z / gn, sn = g1.w / gn;
    h1.z = cc * x1.z - sn * x1.w;
    h1.w = cc * x1.w + sn * x1.z;
  }
  h0.x = h0.x - c0.x + t0.x + EPSF; h0.y = h0.y - c0.y + t0.y + EPSF;
  h0.z = h0.z - c0.z + t0.z + EPSF; h0.w = h0.w - c0.w + t0.w + EPSF;
  h1.x = h1.x - c1.x + t1.x + EPSF; h1.y = h1.y - c1.y + t1.y + EPSF;
  h1.z = h1.z - c1.z + t1.z + EPSF; h1.w = h1.w - c1.w + t1.w + EPSF;

  const float bh = MARGIN + bias_head[u];

  // ---------------- pairwise distances: 16 m's per wave ----------------
  const int mbase = s * (MM / SPLIT) + wid * 16;

  // prefetch all 16 indices (wave-uniform broadcast loads)
  const int4* vp = (const int4*)(v_idx + b * MM + mbase);
  int4 iv0 = vp[0], iv1 = vp[1], iv2 = vp[2], iv3 = vp[3];
  int idxs[16] = {iv0.x, iv0.y, iv0.z, iv0.w, iv1.x, iv1.y, iv1.z, iv1.w,
                  iv2.x, iv2.y, iv2.z, iv2.w, iv3.x, iv3.y, iv3.z, iv3.w};

#pragma unroll
  for (int it = 0; it < 4; ++it) {
    const int va = idxs[4 * it + 0];
    const int vb = idxs[4 * it + 1];
    const int vc = idxs[4 * it + 2];
    const int vd = idxs[4 * it + 3];

    const float4* ta = (const float4*)(emb + (size_t)va * DD);
    const float4* tb = (const float4*)(emb + (size_t)vb * DD);
    const float4* tc = (const float4*)(emb + (size_t)vc * DD);
    const float4* td = (const float4*)(emb + (size_t)vd * DD);
    float4 a0 = ta[2 * lane], a1 = ta[2 * lane + 1];
    float4 b0 = tb[2 * lane], b1 = tb[2 * lane + 1];
    float4 cc0 = tc[2 * lane], cc1 = tc[2 * lane + 1];
    float4 d0 = td[2 * lane], d1 = td[2 * lane + 1];

    float d, ra, rb, rc, rd;
    d = h0.x - a0.x; ra = d * d;
    d = h0.y - a0.y; ra += d * d;
    d = h0.z - a0.z; ra += d * d;
    d = h0.w - a0.w; ra += d * d;
    d = h1.x - a1.x; ra += d * d;
    d = h1.y - a1.y; ra += d * d;
    d = h1.z - a1.z; ra += d * d;
    d = h1.w - a1.w; ra += d * d;

    d = h0.x - b0.x; rb = d * d;
    d = h0.y - b0.y; rb += d * d;
    d = h0.z - b0.z; rb += d * d;
    d = h0.w - b0.w; rb += d * d;
    d = h1.x - b1.x; rb += d * d;
    d = h1.y - b1.y; rb += d * d;
    d = h1.z - b1.z; rb += d * d;
    d = h1.w - b1.w; rb += d * d;

    d = h0.x - cc0.x; rc = d * d;
    d = h0.y - cc0.y; rc += d * d;
    d = h0.z - cc0.z; rc += d * d;
    d = h0.w - cc0.w; rc += d * d;
    d = h1.x - cc1.x; rc += d * d;
    d = h1.y - cc1.y; rc += d * d;
    d = h1.z - cc1.z; rc += d * d;
    d = h1.w - cc1.w; rc += d * d;

    d = h0.x - d0.x; rd = d * d;
    d = h0.y - d0.y; rd += d * d;
    d = h0.z - d0.z; rd += d * d;
    d = h0.w - d0.w; rd += d * d;
    d = h1.x - d1.x; rd += d * d;
    d = h1.y - d1.y; rd += d * d;
    d = h1.z - d1.z; rd += d * d;
    d = h1.w - d1.w; rd += d * d;

#pragma unroll
    for (int off = 32; off; off >>= 1) {
      ra += __shfl_xor(ra, off, 64);
      rb += __shfl_xor(rb, off, 64);
      rc += __shfl_xor(rc, off, 64);
      rd += __shfl_xor(rd, off, 64);
    }

    if (lane == 0) {
      float4 o;
      o.x = bh - sqrtf(ra) + bias_tail[va];
      o.y = bh - sqrtf(rb) + bias_tail[vb];
      o.z = bh - sqrtf(rc) + bias_tail[vc];
      o.w = bh - sqrtf(rd) + bias_tail[vd];
      *(float4*)(out + b * MM + mbase + 4 * it) = o;
    }
  }
}

extern "C" void kernel_launch(void* const* d_in, const int* in_sizes, int n_in,
                              void* d_out, int out_size, void* d_ws, size_t ws_size,
                              hipStream_t stream) {
  const int* u_idx = (const int*)d_in[0];
  const int* r_idx = (const int*)d_in[1];
  const int* v_idx = (const int*)d_in[2];
  const float* emb = (const float*)d_in[3];
  const float* rrot = (const float*)d_in[4];
  const float* rcen = (const float*)d_in[5];
  const float* rtrans = (const float*)d_in[6];
  const float* bias_head = (const float*)d_in[7];
  const float* bias_tail = (const float*)d_in[8];
  float* out = (float*)d_out;

  roth_fused_kernel<<<BB * SPLIT, 256, 0, stream>>>(
      u_idx, r_idx, v_idx, emb, rrot, rcen, rtrans, bias_head, bias_tail, out);
}